// Round 4
// baseline (386.937 us; speedup 1.0000x reference)
//
#include <hip/hip_runtime.h>
#include <math.h>

#define N_ROWS 32768
#define DIM    1024
#define NE     64
#define KTOP   8
#define BK     64
#define NCHUNK (DIM / BK)   // 16

#define COMP(v, c) (reinterpret_cast<const float*>(&(v))[c])

// XOR-swizzled LDS indices (xor with mult-of-4 keeps b128 alignment):
//  x tile:  quad = k4 ^ ((r>>1)&7)  -> A-frag reads conflict-free across rr
//  w tile:  quad = k4 ^ ((e>>3)&7)  -> B-frag reads conflict-free across re
__device__ __forceinline__ int sxi(int r, int k) { return r * BK + (k ^ (((r >> 1) & 7) << 2)); }
__device__ __forceinline__ int swi(int e, int k) { return e * BK + (k ^ (((e >> 3) & 7) << 2)); }

// Block: 256 threads = 4 waves. Wave w: rows [16w,16w+16) x all 64 experts.
// Lane (rr=lane>>3, re=lane&7): 2 rows x 8 experts microtile (acc 16 VGPRs).
// Operands feed from LDS fragments (8-way lane-broadcast => ~10 LDS phases per
// 128 FMA-cycles per wave). x streams HBM->reg->LDS; w re-read per block (L2).
extern "C" __global__ void __launch_bounds__(256, 2)
moe_gate_kernel(const float* __restrict__ x, const float* __restrict__ gw,
                const float* __restrict__ nw, const float* __restrict__ noise,
                float* __restrict__ out0, float* __restrict__ out1,
                float* __restrict__ lossp,
                double* __restrict__ esum, int* __restrict__ ticket) {
    __shared__ float smem[8192];       // 32 KB: xs[0,4096) ws[4096,8192); reused
    __shared__ int   isLast;
    float* xs  = smem;
    float* wsm = smem + 4096;

    const int tid  = threadIdx.x;
    const int lane = tid & 63;
    const int wid  = __builtin_amdgcn_readfirstlane(tid >> 6);   // 0..3 uniform
    const int rr   = lane >> 3;        // row group 0..7
    const int re   = lane & 7;         // expert group 0..7
    const int row0 = blockIdx.x * 64;

    // ---- staging mapping: thread -> (row srow+16i, float4-col skf) ----
    const int srow = tid >> 4;         // 0..15
    const int skf  = tid & 15;
    const float* xg = x  + (size_t)(row0 + srow) * DIM + skf * 4;
    const float* wg = gw + (size_t)srow * DIM + skf * 4;
    int wxa[4], wwa[4];
#pragma unroll
    for (int i = 0; i < 4; ++i) {
        wxa[i] = sxi(srow + 16 * i, skf * 4);
        wwa[i] = swi(srow + 16 * i, skf * 4);
    }

    float4 px[4], pw[4];
#pragma unroll
    for (int i = 0; i < 4; ++i) {      // preload chunk 0
        px[i] = *(const float4*)(xg + (size_t)i * 16 * DIM);
        pw[i] = *(const float4*)(wg + (size_t)i * 16 * DIM);
    }

    float acc[2][8];
#pragma unroll
    for (int i = 0; i < 2; ++i)
#pragma unroll
        for (int j = 0; j < 8; ++j) acc[i][j] = 0.f;

    const int r0 = wid * 16 + rr * 2;  // lane's first (block-local) row

#pragma unroll 1
    for (int kc = 0; kc < NCHUNK; ++kc) {
        __syncthreads();
#pragma unroll
        for (int i = 0; i < 4; ++i) {
            *(float4*)(xs  + wxa[i]) = px[i];
            *(float4*)(wsm + wwa[i]) = pw[i];
        }
        __syncthreads();
        if (kc < NCHUNK - 1) {         // register prefetch of next chunk
            const int ko = (kc + 1) * BK;
#pragma unroll
            for (int i = 0; i < 4; ++i) {
                px[i] = *(const float4*)(xg + (size_t)i * 16 * DIM + ko);
                pw[i] = *(const float4*)(wg + (size_t)i * 16 * DIM + ko);
            }
        }
#pragma unroll 4
        for (int k4 = 0; k4 < BK / 4; ++k4) {
            const int kx = (k4 * 4) ^ (rr << 2);   // swizzled k for x (r0 even)
            const int kw = (k4 * 4) ^ (re << 2);   // swizzled k for w
            float4 a0 = *(const float4*)(xs + r0 * BK + kx);
            float4 a1 = *(const float4*)(xs + (r0 + 1) * BK + kx);
            float4 b[8];
#pragma unroll
            for (int j = 0; j < 8; ++j)
                b[j] = *(const float4*)(wsm + (8 * re + j) * BK + kw);
#pragma unroll
            for (int c = 0; c < 4; ++c)            // 16 indep accs per component
#pragma unroll
                for (int j = 0; j < 8; ++j) {
                    acc[0][j] = fmaf(COMP(a0, c), COMP(b[j], c), acc[0][j]);
                    acc[1][j] = fmaf(COMP(a1, c), COMP(b[j], c), acc[1][j]);
                }
        }
    }

    // ---- logits -> LDS (stride 65), then lane=expert epilogue ----
    __syncthreads();                   // all fragment reads done; reuse smem
    float* lg = smem;                  // [64][65] = 4160 floats
#pragma unroll
    for (int i = 0; i < 2; ++i)
#pragma unroll
        for (int j = 0; j < 8; ++j)
            lg[(r0 + i) * 65 + 8 * re + j] = acc[i][j];
    __syncthreads();

    const float nwl = nw[lane];
    float epart = 0.f;

#pragma unroll 1
    for (int i = 0; i < 16; ++i) {     // wave handles 16 rows, lane = expert
        const int    lrow = wid * 16 + i;
        const size_t grow = (size_t)(row0 + lrow);
        const float  lgv  = lg[lrow * 65 + lane];

        // dense softmax over 64 experts (load-balance mean term)
        float m = lgv;
#pragma unroll
        for (int off = 32; off; off >>= 1) m = fmaxf(m, __shfl_xor(m, off));
        float p = __expf(lgv - m);
        float s = p;
#pragma unroll
        for (int off = 32; off; off >>= 1) s += __shfl_xor(s, off);
        epart += p / s;

        // noisy logits + iterative top-8 argmax (tie -> lower index)
        const float nz    = noise[grow * NE + lane];
        const float noisy = fmaf(nz, nwl, lgv);
        float cur  = noisy;
        bool  sel  = false;
        float mtop = 0.f;
        int   myid = 0;
#pragma unroll
        for (int j = 0; j < KTOP; ++j) {
            float v = cur; int id = lane;
#pragma unroll
            for (int off = 32; off; off >>= 1) {
                float ov = __shfl_xor(v, off);
                int   oi = __shfl_xor(id, off);
                if (ov > v || (ov == v && oi < id)) { v = ov; id = oi; }
            }
            if (j == 0) mtop = v;
            if (lane == id) { sel = true; cur = -INFINITY; }
            if (lane == j) myid = id;
        }

        float swv  = sel ? __expf(noisy - mtop) : 0.f;
        float ssum = swv;
#pragma unroll
        for (int off = 32; off; off >>= 1) ssum += __shfl_xor(ssum, off);

        out0[grow * NE + lane] = swv / ssum;            // coalesced 256 B/row
        if (lane < KTOP) out1[grow * KTOP + lane] = (float)myid;
    }

    // ---- load-balance sums: block partial -> device atomics ----
    float* red = smem + 4224;          // disjoint from lg region
    red[wid * 64 + lane] = epart;
    __syncthreads();
    if (tid < NE) {
        float t = red[tid] + red[64 + tid] + red[128 + tid] + red[192 + tid];
        atomicAdd(&esum[tid], (double)t);
        __threadfence();
    }
    __syncthreads();
    if (tid == 0) {
        int t = atomicAdd(ticket, 1);
        isLast = (t == (int)gridDim.x - 1);
        __threadfence();
    }
    __syncthreads();

    // ---- last block computes the scalar loss (f64) ----
    if (isLast && tid < NE) {
        double v = atomicAdd(&esum[tid], 0.0);          // device-scope read
        double mean = v * (1.0 / 32768.0);
        double d  = mean - (1.0 / 64.0);
        double sq = d * d;
#pragma unroll
        for (int off = 32; off; off >>= 1) sq += __shfl_xor(sq, off);
        if (tid == 0) lossp[0] = (float)(sq * (1.0 / 64.0) * 0.01);
    }
}

extern "C" void kernel_launch(void* const* d_in, const int* in_sizes, int n_in,
                              void* d_out, int out_size, void* d_ws, size_t ws_size,
                              hipStream_t stream) {
    const float* x     = (const float*)d_in[0];   // [32768,1024]
    const float* gw    = (const float*)d_in[1];   // [64,1024]
    const float* nw    = (const float*)d_in[2];   // [64]
    const float* noise = (const float*)d_in[3];   // [32768,64]

    float* out0  = (float*)d_out;                       // [32768,64] gated weights
    float* out1  = out0 + (size_t)N_ROWS * NE;          // [32768,8] ids as f32
    float* lossp = out1 + (size_t)N_ROWS * KTOP;        // scalar loss

    double* esum   = (double*)d_ws;                     // [64]
    int*    ticket = (int*)((char*)d_ws + 512);

    hipMemsetAsync(d_ws, 0, 520, stream);
    moe_gate_kernel<<<N_ROWS / 64, 256, 0, stream>>>(x, gw, nw, noise,
                                                     out0, out1, lossp, esum, ticket);
}